// Round 8
// baseline (276.347 us; speedup 1.0000x reference)
//
#include <hip/hip_runtime.h>
#include <hip/hip_bf16.h>
#include <stdint.h>

// ---------------------------------------------------------------------------
// CharToWord v8: bidirectional char-GRU + attention pooling.
// v7 post-mortem: h_s XOR-swizzle was applied base-first, then +kt*64 carried
// into bit 7 -> read addresses were NOT the inverse of the write swizzle ->
// garbage/NaN. v8 drops the swizzle and uses the v6-proven fragment-linear
// h_s layout (reads conflict-free by construction); keeps all v7 wins:
//  - MFMA operand swap: C[gate][word] = mfma(Whh'_regs, h_LDS); thread owns
//    one word x 4 consecutive hids INSIDE one frag slot -> 1 ds_write_b64
//    (replaces v6's 4 scalar b16 writes that caused 8.4M bank conflicts).
//  - xp table f32 (3 float4 loads, no b2f), one char lookup per thread.
//  - exp2 scale folding into Whh'/xp/bhh_n (zero scale multiplies in gates).
//  - unroll-2 step macro: compile-time buffer parity, reg ping-pong.
// ---------------------------------------------------------------------------

typedef unsigned short u16;
typedef float f32x4 __attribute__((ext_vector_type(4)));
typedef __bf16 bf16x8 __attribute__((ext_vector_type(8)));

#if __has_builtin(__builtin_amdgcn_exp2f)
#define EXP2F(x) __builtin_amdgcn_exp2f(x)
#else
#define EXP2F(x) exp2f(x)
#endif
#if __has_builtin(__builtin_amdgcn_rcpf)
#define RCPF(x) __builtin_amdgcn_rcpf(x)
#else
#define RCPF(x) (1.0f / (x))
#endif

#define LOG2E 1.4426950408889634f

__device__ __forceinline__ u16 f2b(float f) {
  uint32_t u = __builtin_bit_cast(uint32_t, f);
  u = u + 0x7FFFu + ((u >> 16) & 1u);
  return (u16)(u >> 16);
}
__device__ __forceinline__ float b2f(u16 s) {
  uint32_t u = ((uint32_t)s) << 16;
  return __builtin_bit_cast(float, u);
}
__device__ __forceinline__ float fast_tanh(float x) {
  return 1.0f - 2.0f * RCPF(EXP2F(2.0f * LOG2E * x) + 1.0f);
}
__device__ __forceinline__ uint32_t cvtpk(float a, float b) {
  uint32_t r;
  asm("v_cvt_pk_bf16_f32 %0, %1, %2" : "=v"(r) : "v"(a), "v"(b));
  return r;
}

// ---------------------------------------------------------------------------
// prep: grid 448 x 256
//  blocks [0,384)   : xp f32 tables, entry (c,wv,grp,cls,j):
//                     (dot(emb[c],Wih[row]) + bih[row] + (cls<2? bhh[row]:0))
//                     * (cls<2 ? -log2e : 2log2e); row=cls*128+wv*16+grp*4+j
//  blocks [384,432) : Whh frag bf16 (scaled), chunks ((nt*4+kt)*64+lane)*8
//  blocks [432,448) : Wp frag bf16 (UNscaled), chunks ((nt*8+kt)*64+lane)*8
// ---------------------------------------------------------------------------
__global__ void prep_kernel(
    const float* __restrict__ emb,
    const float* __restrict__ wih_f, const float* __restrict__ bih_f,
    const float* __restrict__ wih_b, const float* __restrict__ bih_b,
    const float* __restrict__ bhh_f, const float* __restrict__ bhh_b,
    const float* __restrict__ whh_f_in, const float* __restrict__ whh_b_in,
    const float* __restrict__ wp_in,
    float* __restrict__ xpf_f, float* __restrict__ xpf_b,
    u16* __restrict__ whhf, u16* __restrict__ whhb, u16* __restrict__ wpf) {
  int gid = blockIdx.x * 256 + threadIdx.x;
  if (blockIdx.x < 384) {
    int e = gid;                    // 0..98303
    int d = (e >= 49152) ? 1 : 0;
    int r = e - d * 49152;
    int j = r & 3;
    int e2 = r >> 2;                // 12288
    int cls = e2 % 3;
    int e3 = e2 / 3;                // 4096
    int grp = e3 & 3;
    int e4 = e3 >> 2;               // 1024
    int wv = e4 & 7;
    int c = e4 >> 3;                // 128
    int row = cls * 128 + wv * 16 + grp * 4 + j;
    const float* wih = d ? wih_b : wih_f;
    const float* bih = d ? bih_b : bih_f;
    const float* bhh = d ? bhh_b : bhh_f;
    const float4* e4p = (const float4*)(emb + c * 64);
    const float4* w4p = (const float4*)(wih + row * 64);
    float s = 0.f;
#pragma unroll
    for (int q = 0; q < 16; q++) {
      float4 a = e4p[q], b = w4p[q];
      s += a.x * b.x + a.y * b.y + a.z * b.z + a.w * b.w;
    }
    s += bih[row];
    float scale;
    if (cls < 2) {
      s += bhh[row];
      scale = -LOG2E;
    } else {
      scale = 2.0f * LOG2E;
    }
    (d ? xpf_b : xpf_f)[r] = s * scale;
  } else if (blockIdx.x < 432) {
    int idx = gid - 384 * 256;  // 0..12287
    int d = (idx >= 6144) ? 1 : 0;
    int r = idx - d * 6144;
    int lane = r & 63, kt = (r >> 6) & 3, nt = r >> 8;
    float scale = (nt < 16) ? -LOG2E : 2.0f * LOG2E;  // cls = nt>>3
    int n = nt * 16 + (lane & 15);
    int k0 = kt * 32 + (lane >> 4) * 8;
    const float* w = d ? whh_b_in : whh_f_in;
    u16* o = (d ? whhb : whhf) + r * 8;
    for (int j = 0; j < 8; j++) o[j] = f2b(w[n * 128 + k0 + j] * scale);
  } else {
    int idx = gid - 432 * 256;  // 0..4095
    if (idx < 4096) {
      int lane = idx & 63, kt = (idx >> 6) & 7, nt = idx >> 9;
      int n = nt * 16 + (lane & 15);
      int k0 = kt * 32 + (lane >> 4) * 8;
      u16* o = wpf + idx * 8;
      for (int j = 0; j < 8; j++) o[j] = f2b(wp_in[n * 256 + k0 + j]);
    }
  }
}

// ---------------------------------------------------------------------------
// counting sort by length (bins 1..20); c0 = pad-position attention score.
// ---------------------------------------------------------------------------
__global__ void sort_zero(int* __restrict__ bins) {
  if (threadIdx.x < 32) bins[threadIdx.x] = 0;
}
__global__ void sort_hist(const int* __restrict__ lens, int* __restrict__ bins) {
  __shared__ int hcnt[32];
  int tid = threadIdx.x;
  if (tid < 32) hcnt[tid] = 0;
  __syncthreads();
  int gid = blockIdx.x * 256 + tid;
  int l = lens[gid] & 31;
  atomicAdd(&hcnt[l], 1);
  __syncthreads();
  if (tid < 32 && hcnt[tid]) atomicAdd(&bins[tid], hcnt[tid]);
}
__global__ void sort_scan(const int* __restrict__ bins, int* __restrict__ offsw,
                          const float* __restrict__ bp,
                          const float* __restrict__ ctx,
                          float* __restrict__ c0out) {
  if (threadIdx.x == 0 && blockIdx.x == 0) {
    int off = 0;
    for (int l = 0; l < 32; l++) {
      offsw[l] = off;
      off += bins[l];
    }
    float c0 = 0.f;
    for (int c = 0; c < 128; c++) c0 += fast_tanh(bp[c]) * ctx[c];
    *c0out = c0;
  }
}
__global__ void sort_scat(const int* __restrict__ lens, int* __restrict__ offsw,
                          int* __restrict__ perm) {
  __shared__ int lcnt[32];
  __shared__ int lbase[32];
  int tid = threadIdx.x;
  if (tid < 32) lcnt[tid] = 0;
  __syncthreads();
  int gid = blockIdx.x * 256 + tid;
  int l = lens[gid] & 31;
  int lr = atomicAdd(&lcnt[l], 1);
  __syncthreads();
  if (tid < 32) lbase[tid] = lcnt[tid] ? atomicAdd(&offsw[tid], lcnt[tid]) : 0;
  __syncthreads();
  perm[lbase[l] + lr] = gid;
}

// ---------------------------------------------------------------------------
// gru: grid 2*nbd x 512. bid parity = direction; 16 sorted words/block.
// Operand-swapped: C[gate][word] = mfma(Whh'_regs, h_LDS). Thread (wv,ln):
// word = ln&15, hids = wv*16 + (ln>>4)*4 + r (4 consecutive, one frag slot).
// h_s = fragment-linear [2][kt:4][lane:64][8] bf16 (v6 layout, reads
// conflict-free); write = one ds_write_b64/thread. One barrier/step. LPT.
// ---------------------------------------------------------------------------
__global__ __launch_bounds__(512, 4) void gru_kernel(
    const int* __restrict__ chars, const int* __restrict__ lens,
    const int* __restrict__ perm,
    const float* __restrict__ xpf_f, const float* __restrict__ xpf_b,
    const u16* __restrict__ whhf, const u16* __restrict__ whhb,
    const float* __restrict__ bhh_f, const float* __restrict__ bhh_b,
    u16* __restrict__ hf, u16* __restrict__ hb, int word_off, int nbd) {
  const int bid = blockIdx.x;
  const int dir = bid & 1;
  const int wg = nbd - 1 - (bid >> 1);  // longest-first
  const int tid = threadIdx.x;

  __shared__ int perm_s[16];
  __shared__ unsigned char lens_s[16];
  __shared__ int coff_s[320];      // c*384 (xp float offset), pre-remapped t
  __shared__ u16 h_s[2][2048];     // frag-linear: (kt*64+lane)*8 + j

  if (tid < 16) {
    int p = perm[word_off + wg * 16 + tid];
    perm_s[tid] = p;
    lens_s[tid] = (unsigned char)lens[p];
  }
  for (int i = tid; i < 1024; i += 512) ((uint32_t*)h_s)[i] = 0u;
  __syncthreads();
  for (int i = tid; i < 320; i += 512) {
    int w = i & 15, s = i >> 4;
    int L = lens_s[w];
    int t = dir ? ((s < L) ? (L - 1 - s) : s) : s;
    coff_s[s * 16 + w] = chars[perm_s[w] * 20 + t] * 384;
  }

  const float* xp = dir ? xpf_b : xpf_f;
  const u16* whh = dir ? whhb : whhf;
  const float* bhh = dir ? bhh_b : bhh_f;
  u16* hout = (dir ? hb : hf) + (size_t)wg * 16 * 2560;

  const int wv = tid >> 6, ln = tid & 63, word = ln & 15, grp = ln >> 4;
  const float* xpt = xp + (wv * 4 + grp) * 12;

  // Whh' A-fragments (pre-scaled): 48 VGPRs, once per block
  bf16x8 Wf[3][4];
#pragma unroll
  for (int cls = 0; cls < 3; cls++) {
    int nt = cls * 8 + wv;
#pragma unroll
    for (int kt = 0; kt < 4; kt++)
      Wf[cls][kt] = *(const bf16x8*)(whh + (((nt * 4 + kt) * 64 + ln) << 3));
  }
  // bhh_n (scaled 2log2e) for this thread's 4 hids
  float4 bhn = *(const float4*)(bhh + 256 + wv * 16 + grp * 4);
  bhn.x *= 2.0f * LOG2E; bhn.y *= 2.0f * LOG2E;
  bhn.z *= 2.0f * LOG2E; bhn.w *= 2.0f * LOG2E;

  __syncthreads();  // coff_s + h_s zero ready

  const int Lmax = lens_s[15];  // sorted ascending within block

  // h_s write offset (bytes within a buffer): thread's 4 hids sit at
  // slot (kt_w = wv>>1, lane_w = word | (((wv&1)*2 + (grp>>1))<<4)),
  // byte sub-offset (grp&1)*8. All thread-constant.
  const int hw_off =
      (((wv >> 1) * 64) + (word | (((wv & 1) * 2 + (grp >> 1)) << 4))) * 16 +
      (grp & 1) * 8;
  // store phase: thread -> (word swd, 4-hid slice k4)
  const int swd = tid >> 5;
  const int k4 = (tid & 31) << 2;
  const int sL = lens_s[swd];
  const int hs_off =
      (((k4 >> 5) * 64) + (swd | (((k4 >> 3) & 3) << 4))) * 16 + (k4 & 7) * 2;

  char* hsb = (char*)h_s;

  float hreg[4] = {0.f, 0.f, 0.f, 0.f};
  f32x4 xA0, xA1, xA2, xB0, xB1, xB2;
  {
    int off = coff_s[word];
    xA0 = *(const f32x4*)(xpt + off);
    xA1 = *(const f32x4*)(xpt + off + 4);
    xA2 = *(const f32x4*)(xpt + off + 8);
  }

#define GSTEP(S, PAR, XC0, XC1, XC2, XN0, XN1, XN2)                           \
  {                                                                           \
    if ((S) + 1 < Lmax) {                                                     \
      int off = coff_s[((S) + 1) * 16 + word];                                \
      XN0 = *(const f32x4*)(xpt + off);                                       \
      XN1 = *(const f32x4*)(xpt + off + 4);                                   \
      XN2 = *(const f32x4*)(xpt + off + 8);                                   \
    }                                                                         \
    f32x4 a0 = (f32x4){0.f, 0.f, 0.f, 0.f};                                   \
    f32x4 a1 = (f32x4){0.f, 0.f, 0.f, 0.f};                                   \
    f32x4 a2 = (f32x4){bhn.x, bhn.y, bhn.z, bhn.w};                           \
    _Pragma("unroll")                                                         \
    for (int kt = 0; kt < 4; kt++) {                                          \
      bf16x8 Hf =                                                             \
          *(const bf16x8*)(hsb + (PAR) * 4096 + ((kt * 64 + ln) << 4));       \
      a0 = __builtin_amdgcn_mfma_f32_16x16x32_bf16(Wf[0][kt], Hf, a0, 0, 0, 0); \
      a1 = __builtin_amdgcn_mfma_f32_16x16x32_bf16(Wf[1][kt], Hf, a1, 0, 0, 0); \
      a2 = __builtin_amdgcn_mfma_f32_16x16x32_bf16(Wf[2][kt], Hf, a2, 0, 0, 0); \
    }                                                                         \
    _Pragma("unroll")                                                         \
    for (int r = 0; r < 4; r++) {                                             \
      float rr = RCPF(1.0f + EXP2F(XC0[r] + a0[r]));                          \
      float zz = RCPF(1.0f + EXP2F(XC1[r] + a1[r]));                          \
      float na = fmaf(rr, a2[r], XC2[r]);                                     \
      float nn = fmaf(-2.0f, RCPF(EXP2F(na) + 1.0f), 1.0f);                   \
      hreg[r] = fmaf(zz, hreg[r] - nn, nn);                                   \
    }                                                                         \
    {                                                                         \
      uint2 pk = make_uint2(cvtpk(hreg[0], hreg[1]), cvtpk(hreg[2], hreg[3]));\
      *(uint2*)(hsb + ((PAR) ^ 1) * 4096 + hw_off) = pk;                      \
    }                                                                         \
    __syncthreads();                                                          \
    if ((S) < sL) {                                                           \
      int tdst = dir ? (sL - 1 - (S)) : (S);                                  \
      uint2 v = *(const uint2*)(hsb + ((PAR) ^ 1) * 4096 + hs_off);           \
      *(uint2*)(hout + ((size_t)swd * 20 + tdst) * 128 + k4) = v;             \
    }                                                                         \
  }

  for (int s = 0; s < Lmax; s += 2) {
    GSTEP(s, 0, xA0, xA1, xA2, xB0, xB1, xB2);
    if (s + 1 < Lmax) GSTEP(s + 1, 1, xB0, xB1, xB2, xA0, xA1, xA2);
  }
#undef GSTEP
}

// ---------------------------------------------------------------------------
// attn: grid nbA x 256. 16 sorted words/block, 16 threads/word (facc[16]).
// Online softmax over valid t + pad mass (20-L)*e^{c0-mrun}. LPT order.
// ---------------------------------------------------------------------------
__global__ __launch_bounds__(256, 2) void attn_kernel(
    const u16* __restrict__ hf, const u16* __restrict__ hb,
    const u16* __restrict__ wpf,
    const float* __restrict__ bp, const float* __restrict__ ctx,
    const int* __restrict__ perm, const int* __restrict__ lens,
    const float* __restrict__ c0p,
    float* __restrict__ out, int word_off) {
  const int blk = gridDim.x - 1 - blockIdx.x;  // longest-first
  const int lw0 = blk * 16;

  __shared__ u16 ot_s[4096];       // 8 KiB: Out_t frag layout (16x256)
  __shared__ float part_s[4][16];
  __shared__ int perm_s[16];
  __shared__ unsigned char lens_s[16];

  const int tid = threadIdx.x;
  const int wv = tid >> 6, ln = tid & 63, col = ln & 15, grp = ln >> 4;
  const int sw = tid >> 4;   // this thread's word (16 threads per word)
  const int seg = tid & 15;  // 16-dim segment of the 256-dim output

  if (tid < 16) {
    int p = perm[word_off + lw0 + tid];
    perm_s[tid] = p;
    lens_s[tid] = (unsigned char)lens[p];
  }
  __syncthreads();
  const int Lmax = lens_s[15];  // sorted ascending within block
  const int Lw = lens_s[sw];

  float bpv[2], ctxv[2];
#pragma unroll
  for (int n = 0; n < 2; n++) {
    int nt = wv + n * 4;
    bpv[n] = bp[nt * 16 + col];
    ctxv[n] = ctx[nt * 16 + col];
  }

  float facc[16];
#pragma unroll
  for (int i = 0; i < 16; i++) facc[i] = 0.f;
  float mrun = -3.0e38f, drun = 0.f;

  // seg 0..7 -> hf dims [seg*16,+16); seg 8..15 -> hb dims [(seg-8)*16,+16)
  const u16* srcbase =
      ((seg < 8) ? hf : hb) + (size_t)(lw0 + sw) * 2560 + (seg & 7) * 16;

  uint4 vn[2];
#pragma unroll
  for (int q = 0; q < 2; q++) vn[q] = *(const uint4*)(srcbase + q * 8);

  for (int t = 0; t < Lmax; t++) {
    uint4 v[2];
    v[0] = vn[0];
    v[1] = vn[1];

    // stage Out_t into frag layout: k = seg*16 + q*8
#pragma unroll
    for (int q = 0; q < 2; q++) {
      int idx = seg * 2 + q;           // k>>3, 0..31
      int kt = idx >> 2;               // k>>5
      int lane_a = sw | ((idx & 3) << 4);
      *(uint4*)(ot_s + ((kt * 64 + lane_a) << 3)) = v[q];
    }
    // prefetch next t (hidden under MFMA/score)
    if (t + 1 < Lmax) {
      const u16* src = srcbase + (t + 1) * 128;
#pragma unroll
      for (int q = 0; q < 2; q++) vn[q] = *(const uint4*)(src + q * 8);
    }
    __syncthreads();

    // proj = Out_t @ Wp^T + bp (Wp frags from L2)
    f32x4 acc[2];
#pragma unroll
    for (int n = 0; n < 2; n++) acc[n] = (f32x4){bpv[n], bpv[n], bpv[n], bpv[n]};

#pragma unroll
    for (int kt = 0; kt < 8; kt++) {
      bf16x8 Af = *(const bf16x8*)(ot_s + ((kt * 64 + ln) << 3));
#pragma unroll
      for (int n = 0; n < 2; n++) {
        int nt = wv + n * 4;
        bf16x8 Bf = *(const bf16x8*)(wpf + (((nt * 8 + kt) * 64 + ln) << 3));
        acc[n] = __builtin_amdgcn_mfma_f32_16x16x32_bf16(Af, Bf, acc[n], 0, 0, 0);
      }
    }

    // score partials: tanh(proj)*ctx summed over cols; words at (grp*4+r)
#pragma unroll
    for (int r = 0; r < 4; r++) {
      float p = fast_tanh(acc[0][r]) * ctxv[0] + fast_tanh(acc[1][r]) * ctxv[1];
      p += __shfl_xor(p, 1, 64);
      p += __shfl_xor(p, 2, 64);
      p += __shfl_xor(p, 4, 64);
      p += __shfl_xor(p, 8, 64);
      if (col == 0) part_s[wv][grp * 4 + r] = p;
    }
    __syncthreads();

    float sc = part_s[0][sw] + part_s[1][sw] + part_s[2][sw] + part_s[3][sw];

    if (t < Lw) {
      float mnew = fmaxf(mrun, sc);
      float scale = EXP2F(LOG2E * (mrun - mnew));
      float e = EXP2F(LOG2E * (sc - mnew));
      drun = drun * scale + e;
      mrun = mnew;
#pragma unroll
      for (int q = 0; q < 2; q++) {
        const u16* pv = (const u16*)&v[q];
#pragma unroll
        for (int j = 0; j < 8; j++)
          facc[q * 8 + j] = facc[q * 8 + j] * scale + e * b2f(pv[j]);
      }
    }
  }

  // reference semantics: softmax over all 20 positions; pad rows are zero
  // with constant score c0 -> denominator-only mass.
  drun += (float)(20 - Lw) * EXP2F(LOG2E * (*c0p - mrun));

  float inv = RCPF(drun);
  float* dst = out + (size_t)perm_s[sw] * 256 + seg * 16;
#pragma unroll
  for (int i = 0; i < 4; i++) {
    float4 o = make_float4(facc[i * 4] * inv, facc[i * 4 + 1] * inv,
                           facc[i * 4 + 2] * inv, facc[i * 4 + 3] * inv);
    *(float4*)(dst + i * 4) = o;
  }
}

// ---------------------------------------------------------------------------
extern "C" void kernel_launch(void* const* d_in, const int* in_sizes, int n_in,
                              void* d_out, int out_size, void* d_ws, size_t ws_size,
                              hipStream_t stream) {
  const int* chars = (const int*)d_in[0];
  const int* lens = (const int*)d_in[1];
  const float* emb = (const float*)d_in[2];
  const float* wih_f = (const float*)d_in[3];
  const float* whh_f = (const float*)d_in[4];
  const float* bih_f = (const float*)d_in[5];
  const float* bhh_f = (const float*)d_in[6];
  const float* wih_b = (const float*)d_in[7];
  const float* whh_b = (const float*)d_in[8];
  const float* bih_b = (const float*)d_in[9];
  const float* bhh_b = (const float*)d_in[10];
  const float* wp = (const float*)d_in[11];
  const float* bp = (const float*)d_in[12];
  const float* ctx = (const float*)d_in[13];
  float* outp = (float*)d_out;

  uint8_t* ws = (uint8_t*)d_ws;
  float* xpf_f = (float*)(ws + 0);            // 192 KiB (49152 f32)
  float* xpf_b = (float*)(ws + 196608);       // 192 KiB
  u16* whhf = (u16*)(ws + 393216);            // 96 KiB
  u16* whhb = (u16*)(ws + 491520);            // 96 KiB
  u16* wpf = (u16*)(ws + 589824);             // 64 KiB
  int* bins = (int*)(ws + 655360);            // 128 B
  int* offsw = (int*)(ws + 655488);           // 128 B
  float* c0p = (float*)(ws + 655616);         // 64 B
  int* permp = (int*)(ws + 655680);           // 128 KiB
  const size_t H_OFF = 1048576;

  prep_kernel<<<448, 256, 0, stream>>>(emb, wih_f, bih_f, wih_b, bih_b, bhh_f,
                                       bhh_b, whh_f, whh_b, wp, xpf_f, xpf_b,
                                       whhf, whhb, wpf);
  sort_zero<<<1, 64, 0, stream>>>(bins);
  sort_hist<<<128, 256, 0, stream>>>(lens, bins);
  sort_scan<<<1, 64, 0, stream>>>(bins, offsw, bp, ctx, c0p);
  sort_scat<<<128, 256, 0, stream>>>(lens, offsw, permp);

  const size_t per_word = 20 * 128 * 2 * 2;  // hf+hb bytes per word
  size_t avail = (ws_size > H_OFF) ? (ws_size - H_OFF) : 0;
  int maxw = (int)(avail / per_word) & ~63;
  if (maxw > 32768) maxw = 32768;
  if (maxw < 64) maxw = 64;

  for (int done = 0; done < 32768;) {
    int nw = (32768 - done < maxw) ? (32768 - done) : maxw;
    u16* hfp = (u16*)(ws + H_OFF);
    u16* hbp = hfp + (size_t)nw * 2560;
    int nbd = nw / 16;
    gru_kernel<<<2 * nbd, 512, 0, stream>>>(chars, lens, permp, xpf_f, xpf_b,
                                            whhf, whhb, bhh_f, bhh_b, hfp, hbp,
                                            done, nbd);
    attn_kernel<<<nw / 16, 256, 0, stream>>>(hfp, hbp, wpf, bp, ctx, permp,
                                             lens, c0p, outp, done);
    done += nw;
  }
}